// Round 15
// baseline (72.321 us; speedup 1.0000x reference)
//
#include <hip/hip_runtime.h>
#include <stdint.h>

#define BATCH 256
#define INF   1024
#define OUTF  128
#define NN    1024      // OUTF*KD
#define OROW  1152      // INF + OUTF

#define XCH   2048      // f32 per x chunk: 32 rows x 64
#define TCH   2112      // f32 per T chunk: 8 blocks x 264 (+8 pad per block)
#define NBUF  6         // 99840 B LDS -> 1 block/CU, depth-5 pipeline

typedef __attribute__((ext_vector_type(8))) short short8;
typedef __attribute__((ext_vector_type(4))) float f32x4;

__device__ __forceinline__ short8 cvt8v(f32x4 lo, f32x4 hi) {
    union { short8 s; uint32_t u[4]; } r;
    asm("v_cvt_pk_bf16_f32 %0, %1, %2" : "=v"(r.u[0]) : "v"(lo[0]), "v"(lo[1]));
    asm("v_cvt_pk_bf16_f32 %0, %1, %2" : "=v"(r.u[1]) : "v"(lo[2]), "v"(lo[3]));
    asm("v_cvt_pk_bf16_f32 %0, %1, %2" : "=v"(r.u[2]) : "v"(hi[0]), "v"(hi[1]));
    asm("v_cvt_pk_bf16_f32 %0, %1, %2" : "=v"(r.u[3]) : "v"(hi[2]), "v"(hi[3]));
    return r.s;
}
__device__ __forceinline__ short8 cvt8s(float a, float b, float c, float d,
                                        float e, float f, float g, float h) {
    union { short8 s; uint32_t u[4]; } r;
    asm("v_cvt_pk_bf16_f32 %0, %1, %2" : "=v"(r.u[0]) : "v"(a), "v"(b));
    asm("v_cvt_pk_bf16_f32 %0, %1, %2" : "=v"(r.u[1]) : "v"(c), "v"(d));
    asm("v_cvt_pk_bf16_f32 %0, %1, %2" : "=v"(r.u[2]) : "v"(e), "v"(f));
    asm("v_cvt_pk_bf16_f32 %0, %1, %2" : "=v"(r.u[3]) : "v"(g), "v"(h));
    return r.s;
}

// R3-verified staging (identical index math): per K=64 chunk, 4 waves stage
// x-tile 32 rows x 64 f32 (seg^row&7 XOR on GLOBAL src) + T-tile 64 k x 32 f32
// (8-k blocks at 264-f32 pitch). 4 instrs/wave/chunk.
__device__ __forceinline__ void stage_xt(
    const float* __restrict__ x, const float* __restrict__ T,
    float* xbuf, float* tbuf, int a0, int n0, int c, int wave, int lane)
{
    {   const int r = lane >> 4, seg = lane & 15;
        #pragma unroll
        for (int p = 0; p < 2; ++p) {
            const int i = wave * 2 + p;
            const int row = i * 4 + r;
            const float* src = x + (size_t)(a0 + row) * INF + c * 64 + ((seg ^ (row & 7)) << 2);
            float* dst = xbuf + i * 256;
            __builtin_amdgcn_global_load_lds(
                (const __attribute__((address_space(1))) unsigned int*)src,
                (__attribute__((address_space(3))) unsigned int*)dst, 16, 0, 0);
        }
    }
    {   const int kr = lane >> 3, seg = lane & 7;
        #pragma unroll
        for (int p = 0; p < 2; ++p) {
            const int i = wave * 2 + p;
            const int k = i * 8 + kr;
            const float* src = T + (size_t)(c * 64 + k) * NN + n0 + (seg << 2);
            float* dst = tbuf + i * 264;
            __builtin_amdgcn_global_load_lds(
                (const __attribute__((address_space(1))) unsigned int*)src,
                (__attribute__((address_space(3))) unsigned int*)dst, 16, 0, 0);
        }
    }
}

// One K=64 step, two K=32 substeps. Gate + s_barrier + reads all inside asm
// (R7 trick extended): compiler sees no C-level LDS read -> no vmcnt(0) drain;
// barrier makes cross-wave staged data safe; counted vmcnt keeps depth-5 alive.
#define GSTEP(c, VM) do {                                                     \
    const uint32_t bb = xrow + (uint32_t)(((c) % NBUF) * (XCH * 4));          \
    const uint32_t tb = tcol + (uint32_t)(((c) % NBUF) * (TCH * 4));          \
    f32x4 av0, av1; float b0,b1,b2,b3,b4,b5,b6,b7;                            \
    asm volatile(                                                             \
        "s_waitcnt vmcnt(" #VM ")\n\t"                                        \
        "s_barrier\n\t"                                                       \
        "ds_read_b128 %0, %10\n\t"                                            \
        "ds_read_b128 %1, %11\n\t"                                            \
        "ds_read_b32 %2, %12\n\t"                                             \
        "ds_read_b32 %3, %12 offset:128\n\t"                                  \
        "ds_read_b32 %4, %12 offset:256\n\t"                                  \
        "ds_read_b32 %5, %12 offset:384\n\t"                                  \
        "ds_read_b32 %6, %12 offset:512\n\t"                                  \
        "ds_read_b32 %7, %12 offset:640\n\t"                                  \
        "ds_read_b32 %8, %12 offset:768\n\t"                                  \
        "ds_read_b32 %9, %12 offset:896\n\t"                                  \
        "s_waitcnt lgkmcnt(0)"                                                \
        : "=&v"(av0), "=&v"(av1), "=&v"(b0), "=&v"(b1), "=&v"(b2), "=&v"(b3), \
          "=&v"(b4), "=&v"(b5), "=&v"(b6), "=&v"(b7)                          \
        : "v"(bb + gA00), "v"(bb + gA01), "v"(tb)                             \
        : "memory");                                                          \
    accA = __builtin_amdgcn_mfma_f32_16x16x32_bf16(                           \
        cvt8v(av0, av1), cvt8s(b0,b1,b2,b3,b4,b5,b6,b7), accA, 0, 0, 0);      \
    f32x4 av2, av3; float c0,c1,c2,c3,c4,c5,c6,c7;                            \
    asm volatile(                                                             \
        "ds_read_b128 %0, %10\n\t"                                            \
        "ds_read_b128 %1, %11\n\t"                                            \
        "ds_read_b32 %2, %12 offset:4224\n\t"                                 \
        "ds_read_b32 %3, %12 offset:4352\n\t"                                 \
        "ds_read_b32 %4, %12 offset:4480\n\t"                                 \
        "ds_read_b32 %5, %12 offset:4608\n\t"                                 \
        "ds_read_b32 %6, %12 offset:4736\n\t"                                 \
        "ds_read_b32 %7, %12 offset:4864\n\t"                                 \
        "ds_read_b32 %8, %12 offset:4992\n\t"                                 \
        "ds_read_b32 %9, %12 offset:5120\n\t"                                 \
        "s_waitcnt lgkmcnt(0)"                                                \
        : "=&v"(av2), "=&v"(av3), "=&v"(c0), "=&v"(c1), "=&v"(c2), "=&v"(c3), \
          "=&v"(c4), "=&v"(c5), "=&v"(c6), "=&v"(c7)                          \
        : "v"(bb + gA10), "v"(bb + gA11), "v"(tb)                             \
        : "memory");                                                          \
    accB = __builtin_amdgcn_mfma_f32_16x16x32_bf16(                           \
        cvt8v(av2, av3), cvt8s(c0,c1,c2,c3,c4,c5,c6,c7), accB, 0, 0, 0);      \
} while (0)

// K1: M = x @ T (256x1024 fp32 out), straight from fp32 inputs. 256 blocks =
// 8 a-tiles x 32 n-tiles of 32x32; 4 waves, wave (h,g) owns a 16x16 quadrant,
// full K. Depth-5 barriered DMA pipeline with in-asm gates.
__global__ __launch_bounds__(256) void gemm_kernel(
    const float* __restrict__ x, const float* __restrict__ T,
    float* __restrict__ M)
{
    __shared__ __align__(16) float xls[NBUF * XCH];   // 48 KB
    __shared__ __align__(16) float tls[NBUF * TCH];   // 49.5 KB  (total -> 1 blk/CU)

    const int bid = blockIdx.x;
    const int a0 = (bid & 7) << 5;
    const int n0 = (bid >> 3) << 5;
    const int t = threadIdx.x, wave = t >> 6, lane = t & 63;
    const int rc = lane & 15, quad = lane >> 4, r7 = rc & 7;
    const int h = wave >> 1, g = wave & 1;
    const int rloc = h * 16 + rc;       // A row within tile
    const int cn = g * 16 + rc;         // B col within tile

    // Prologue: chunks 0..4 (20 instrs/wave), drained once at the barrier.
    for (int c = 0; c < 5; ++c)
        stage_xt(x, T, xls + c * XCH, tls + c * TCH, a0, n0, c, wave, lane);
    asm volatile("s_waitcnt vmcnt(0)" ::: "memory");
    __syncthreads();

    f32x4 accA = {0.f, 0.f, 0.f, 0.f}, accB = {0.f, 0.f, 0.f, 0.f};
    const uint32_t xrow = (uint32_t)(uintptr_t)(&xls[0]) + (uint32_t)(rloc * 256);
    const uint32_t tcol = (uint32_t)(uintptr_t)(&tls[0]) + (uint32_t)((quad * 264 + cn) * 4);
    const uint32_t gA00 = (uint32_t)(((quad * 2 + 0) ^ r7) << 4);
    const uint32_t gA01 = (uint32_t)(((quad * 2 + 1) ^ r7) << 4);
    const uint32_t gA10 = (uint32_t)(((8 + quad * 2 + 0) ^ r7) << 4);
    const uint32_t gA11 = (uint32_t)(((8 + quad * 2 + 1) ^ r7) << 4);

    // Steady state: gate(16) == "chunks <= c landed" (4 instrs/wave/chunk,
    // chunks c+1..c+4 in flight). Stage c+5 after the in-asm barrier.
    for (int c = 0; c <= 10; ++c) {
        GSTEP(c, 16);
        stage_xt(x, T, xls + ((c + 5) % NBUF) * XCH, tls + ((c + 5) % NBUF) * TCH,
                 a0, n0, c + 5, wave, lane);
    }
    GSTEP(11, 16);
    GSTEP(12, 12);
    GSTEP(13, 8);
    GSTEP(14, 4);
    GSTEP(15, 0);

    // C/D layout: col = lane&15, row = quad*4 + r  [m89/m91; R3-verified write]
    #pragma unroll
    for (int r = 0; r < 4; ++r)
        M[(size_t)(a0 + h * 16 + quad * 4 + r) * NN + n0 + g * 16 + rc]
            = accA[r] + accB[r];
}

// K2: 256 blocks = (o, a-half), 512 threads. DMA-stages the private 8 KB
// M-slice [256 rows x 8], pair phase (R9-verified structure, pitch 8), direct
// c write. Also carries the x -> out copy (row bid), overlapping the gap.
__global__ __launch_bounds__(512) void pair_kernel(
    const float* __restrict__ x, const float* __restrict__ M,
    float* __restrict__ out)
{
    __shared__ __align__(16) float Mloc[256 * 8];   // 8 KB, packed rows
    __shared__ float red[512];

    const int bid = blockIdx.x;
    const int o = bid >> 1, half = bid & 1;
    const int t = threadIdx.x, wave = t >> 6, lane = t & 63;

    // x copy: row bid (4 KB), one float4 per thread t<256.
    if (t < 256) {
        float4 v = *(const float4*)(x + (size_t)bid * INF + t * 4);
        *(float4*)(out + (size_t)bid * OROW + t * 4) = v;
    }
    // DMA the slice: wave w -> rows [32w,32w+32), 2 lanes per row (16 B each).
    {
        const float* src = M + (size_t)(wave * 32 + (lane >> 1)) * NN
                             + o * 8 + (lane & 1) * 4;
        float* dst = Mloc + wave * 256;
        __builtin_amdgcn_global_load_lds(
            (const __attribute__((address_space(1))) unsigned int*)src,
            (__attribute__((address_space(3))) unsigned int*)dst, 16, 0, 0);
    }
    asm volatile("s_waitcnt vmcnt(0)" ::: "memory");
    __syncthreads();

    const int ar = t & 127;            // a-row within half
    const int bq = t >> 7;             // 0..3, wave-uniform -> LDS broadcast
    const int a = half * 128 + ar;
    f32x4 m0 = *(const f32x4*)(Mloc + a * 8);
    f32x4 m1 = *(const f32x4*)(Mloc + a * 8 + 4);
    float ssum = 0.f;
    #pragma unroll 4
    for (int j = 0; j < 64; ++j) {
        const float* qp = Mloc + (bq * 64 + j) * 8;
        f32x4 q0 = *(const f32x4*)(qp);
        f32x4 q1 = *(const f32x4*)(qp + 4);
        float d = fabsf(m0[0] - q0[0]) + fabsf(m0[1] - q0[1])
                + fabsf(m0[2] - q0[2]) + fabsf(m0[3] - q0[3])
                + fabsf(m1[0] - q1[0]) + fabsf(m1[1] - q1[1])
                + fabsf(m1[2] - q1[2]) + fabsf(m1[3] - q1[3]);
        ssum += __expf(-d);
    }
    red[t] = ssum;
    __syncthreads();
    if (t < 128) {
        float s = red[t] + red[t + 128] + red[t + 256] + red[t + 384];
        out[(size_t)(half * 128 + t) * OROW + INF + o] = s - 1.0f;  // -1 = self term
    }
}

extern "C" void kernel_launch(void* const* d_in, const int* in_sizes, int n_in,
                              void* d_out, int out_size, void* d_ws, size_t ws_size,
                              hipStream_t stream) {
    const float* x = (const float*)d_in[0];
    const float* T = (const float*)d_in[1];
    float* out = (float*)d_out;
    float* M = (float*)d_ws;           // 1 MB workspace

    gemm_kernel<<<256, 256, 0, stream>>>(x, T, M);
    pair_kernel<<<256, 512, 0, stream>>>(x, M, out);
}